// Round 9
// baseline (1657.395 us; speedup 1.0000x reference)
//
#include <hip/hip_runtime.h>
#include <stdint.h>
#include <stddef.h>

// QuantizedColumnParallel: y[4096,16384] = x[4096,4096] @ (wq[16384,4096]*scale)^T + bias
// R9: supply-byte model (fits R3/R4/R6/R7/R8 within 5%): time = operand bytes
// moved into CUs / ~6.2 TB/s. Lever: arithmetic intensity. 256x512 tile with
// 1024 threads (16 waves, 2Mx8N, per-wave 128x64 = proven acc[8][4] structure).
// Supply = MNK(1/256+1/512) = 1.6 GB (0.75x of 256^2). Triple-buffer 144 KB,
// stage t+2, counted vmcnt(3). No SGB (R8 reverted), R6 plain schedule.

#define M_TOT 4096
#define N_TOT 16384
#define K_TOT 4096
#define NT    64          // K-tiles
#define BM    256
#define BN    512

typedef __attribute__((ext_vector_type(4))) int      v4i;
typedef __attribute__((ext_vector_type(8))) _Float16 f16x8;
typedef __attribute__((ext_vector_type(4))) float    f32x4;

#define GLOAD_LDS16(g, l) __builtin_amdgcn_global_load_lds(                  \
    (const __attribute__((address_space(1))) void*)(g),                      \
    (__attribute__((address_space(3))) void*)(l), 16, 0, 0)

// ---------------- conversion pre-passes ----------------

__global__ __launch_bounds__(256) void cvt_x_i8(const float* __restrict__ x,
                                                signed char* __restrict__ o,
                                                float* __restrict__ sx) {
  const int row = blockIdx.x;
  const int tid = threadIdx.x;
  const float* xr = x + (size_t)row * K_TOT;
  float4 v[4];
  float mx = 0.f;
#pragma unroll
  for (int j = 0; j < 4; ++j) {
    v[j] = ((const float4*)xr)[tid * 4 + j];
    mx = fmaxf(mx, fmaxf(fmaxf(fabsf(v[j].x), fabsf(v[j].y)),
                         fmaxf(fabsf(v[j].z), fabsf(v[j].w))));
  }
#pragma unroll
  for (int off = 32; off; off >>= 1) mx = fmaxf(mx, __shfl_xor(mx, off));
  __shared__ float wm[4];
  if ((tid & 63) == 0) wm[tid >> 6] = mx;
  __syncthreads();
  const float m4 = fmaxf(fmaxf(wm[0], wm[1]), fmaxf(wm[2], wm[3]));
  const float smax = fmaxf(m4, 1e-6f);
  const float inv  = 127.0f / smax;
  if (tid == 0) sx[row] = smax / 127.0f;
  int p[4];
#pragma unroll
  for (int j = 0; j < 4; ++j) {
    int q0 = (int)rintf(v[j].x * inv), q1 = (int)rintf(v[j].y * inv);
    int q2 = (int)rintf(v[j].z * inv), q3 = (int)rintf(v[j].w * inv);
    q0 = max(-127, min(127, q0)); q1 = max(-127, min(127, q1));
    q2 = max(-127, min(127, q2)); q3 = max(-127, min(127, q3));
    p[j] = (q0 & 255) | ((q1 & 255) << 8) | ((q2 & 255) << 16) | (q3 << 24);
  }
  ((int4*)(o + (size_t)row * K_TOT))[tid] = make_int4(p[0], p[1], p[2], p[3]);
}

__global__ __launch_bounds__(256) void cvt_w_i8(const int* __restrict__ w,
                                                signed char* __restrict__ o, int n16) {
  const int stride = gridDim.x * blockDim.x;
  for (int i = blockIdx.x * blockDim.x + threadIdx.x; i < n16; i += stride) {
    int p[4];
#pragma unroll
    for (int j = 0; j < 4; ++j) {
      int4 a = ((const int4*)w)[i * 4 + j];
      p[j] = (a.x & 255) | ((a.y & 255) << 8) | ((a.z & 255) << 16) | (a.w << 24);
    }
    ((int4*)o)[i] = make_int4(p[0], p[1], p[2], p[3]);
  }
}

// ---------------- i8 GEMM: 256x512 tile, 16 waves, triple-buffered ----------------

// Stage A region (256 rows x 64 B = 16 KiB): 1 x gload_lds(16B)/thread (1024 thr).
// Stage B region (512 rows x 64 B = 32 KiB): 2 x gload_lds(16B)/thread.
// LDS dest linear; XOR swizzle on GLOBAL source chunk (rule #21), conflict-free
// (verified R3..R8: SQ_LDS_BANK_CONFLICT = 0; row geometry 64B/4-chunk unchanged).
__device__ __forceinline__ void stage_A(const signed char* __restrict__ g,
                                        size_t kbyte, signed char* l, int tid) {
  const int row = tid >> 2;              // 0..255
  const int sc  = (tid & 3) ^ ((row >> 1) & 3);
  GLOAD_LDS16(g + (size_t)row * K_TOT + kbyte + sc * 16, l + tid * 16);
}

__device__ __forceinline__ void stage_B(const signed char* __restrict__ g,
                                        size_t kbyte, signed char* l, int tid) {
#pragma unroll
  for (int j = 0; j < 2; ++j) {
    const int ci  = j * 1024 + tid;      // 0..2047 16B-chunks
    const int row = ci >> 2;             // 0..511
    const int sc  = (ci & 3) ^ ((row >> 1) & 3);
    GLOAD_LDS16(g + (size_t)row * K_TOT + kbyte + sc * 16, l + ci * 16);
  }
}

// Swizzled fragment read: row r, 16B chunk hi (0..3). 2-way aliasing = free.
__device__ __forceinline__ v4i fragi(const signed char* region, int r, int hi) {
  return *(const v4i*)(region + r * 64 + ((hi ^ ((r >> 1) & 3)) << 4));
}

#define BAR()    __builtin_amdgcn_s_barrier()

__global__ __launch_bounds__(1024) void gemm_i8(
    const signed char* __restrict__ A8, const signed char* __restrict__ B8,
    const float* __restrict__ sx, const float* __restrict__ scale_p,
    const float* __restrict__ bias, float* __restrict__ out)
{
  // 3 buffers x (A 16K + B 32K) = 144 KiB -> 1 block/CU
  __shared__ __align__(16) signed char lds[3][49152];

  const int tid  = threadIdx.x;
  const int lane = tid & 63;
  const int wave = tid >> 6;           // 0..15
  const int wr = wave >> 3;            // 0..1 (M)
  const int wc = wave & 7;             // 0..7 (N)
  const int lr = lane & 15;
  const int hi = lane >> 4;

  // XCD swizzle: 512 wg, 8 XCDs, 64 contiguous per XCD; bm fast (16) so the
  // 16 blocks sharing a bn panel (B panel 2 MB <= 4 MB L2) sit on one XCD.
  const int bid = blockIdx.x;
  const int wg  = (bid & 7) * 64 + (bid >> 3);
  const int bm  = wg & 15;
  const int bn  = wg >> 4;             // 0..31
  const int arow0 = bm * BM;
  const int brow0 = bn * BN;

  const signed char* Ag = A8 + (size_t)arow0 * K_TOT;
  const signed char* Bg = B8 + (size_t)brow0 * K_TOT;

  v4i acc[8][4];
#pragma unroll
  for (int m = 0; m < 8; ++m)
#pragma unroll
    for (int n = 0; n < 4; ++n)
      acc[m][n] = (v4i){0, 0, 0, 0};

  // ---- prologue: stage tiles 0,1 (3 loads/thread each); vmcnt(3) => tile0 landed.
  stage_A(Ag, 0,  &lds[0][0],     tid);
  stage_B(Bg, 0,  &lds[0][16384], tid);
  stage_A(Ag, 64, &lds[1][0],     tid);
  stage_B(Bg, 64, &lds[1][16384], tid);
  asm volatile("s_waitcnt vmcnt(3)" ::: "memory");
  BAR();

  for (int t = 0; t < NT; ++t) {
    const signed char* At = &lds[t % 3][0];
    const signed char* Bt = &lds[t % 3][16384];

    // Stage t+2 first (latency starts earliest).
    if (t + 2 < NT) {
      const size_t k2 = (size_t)(t + 2) * 64;
      signed char* L2 = &lds[(t + 2) % 3][0];
      stage_A(Ag, k2, L2, tid);
      stage_B(Bg, k2, L2 + 16384, tid);
    }

    // 12 frag reads + 32 MFMAs, unpinned (compiler interleaves lgkmcnt).
    v4i af[8], bf[4];
#pragma unroll
    for (int m = 0; m < 8; ++m) af[m] = fragi(At, wr * 128 + m * 16 + lr, hi);
#pragma unroll
    for (int n = 0; n < 4; ++n) bf[n] = fragi(Bt, wc * 64 + n * 16 + lr, hi);
#pragma unroll
    for (int m = 0; m < 8; ++m)
#pragma unroll
      for (int n = 0; n < 4; ++n)
        acc[m][n] = __builtin_amdgcn_mfma_i32_16x16x64_i8(af[m], bf[n], acc[m][n], 0, 0, 0);

    // Publish t+1 (oldest 3 landed), keep t+2 (youngest 3) in flight.
    if (t < NT - 2) asm volatile("s_waitcnt vmcnt(3)" ::: "memory");
    else            asm volatile("s_waitcnt vmcnt(0)" ::: "memory");
    BAR();
  }

  // ---- epilogue: y = acc * (sx[row]*scale) + bias.
  // C/D map (dtype-independent): col=lane&15, row=(lane>>4)*4+reg.
  const float s = scale_p[0];
  float bv[4];
#pragma unroll
  for (int n = 0; n < 4; ++n) bv[n] = bias[brow0 + wc * 64 + n * 16 + lr];
#pragma unroll
  for (int mi = 0; mi < 8; ++mi) {
    const int row0 = arow0 + wr * 128 + (mi >> 2) * 64 + (mi & 3) * 16 + hi * 4;
    float sc4[4];
#pragma unroll
    for (int j = 0; j < 4; ++j) sc4[j] = sx[row0 + j] * s;
#pragma unroll
    for (int n = 0; n < 4; ++n) {
      const int col = brow0 + wc * 64 + n * 16 + lr;
      const v4i v = acc[mi][n];
#pragma unroll
      for (int j = 0; j < 4; ++j)
        out[(size_t)(row0 + j) * N_TOT + col] = (float)v[j] * sc4[j] + bv[n];
    }
  }
}

// ---------------- fallback (no workspace): f16 DIRECT 128^2 kernel ----------------

__global__ __launch_bounds__(256) void gemm_direct(
    const float* __restrict__ Xf, const int* __restrict__ Wq,
    const float* __restrict__ scale_p, const float* __restrict__ bias,
    float* __restrict__ out)
{
  __shared__ _Float16 ldsA[128 * 64];
  __shared__ _Float16 ldsB[128 * 64];
  const int tid = threadIdx.x, lane = tid & 63, wave = tid >> 6;
  const int wr = wave >> 1, wc = wave & 1;
  const int bid = blockIdx.x;
  const int wg  = (bid & 7) * 512 + (bid >> 3);
  const int arow0 = (wg & 31) * 128, brow0 = (wg >> 5) * 128;
  f32x4 acc[4][4];
#pragma unroll
  for (int m = 0; m < 4; ++m)
#pragma unroll
    for (int n = 0; n < 4; ++n) acc[m][n] = (f32x4){0.f, 0.f, 0.f, 0.f};
  const int srow = tid >> 3, schunk = tid & 7;
  const int lr = lane & 15, hi = lane >> 4;
  for (int kt = 0; kt < K_TOT / 64; ++kt) {
    const size_t kbase = (size_t)kt * 64;
    __syncthreads();
#pragma unroll
    for (int i = 0; i < 4; ++i) {
      const int row = i * 32 + srow;
      const int p = schunk ^ (row & 7);
      const float* gx = Xf + (size_t)(arow0 + row) * K_TOT + kbase + schunk * 8;
      const int*   gw = Wq + (size_t)(brow0 + row) * K_TOT + kbase + schunk * 8;
      float4 x0 = ((const float4*)gx)[0];
      float4 x1 = ((const float4*)gx)[1];
      int4   w0 = ((const int4*)gw)[0];
      int4   w1 = ((const int4*)gw)[1];
      f16x8 ha = { (_Float16)x0.x, (_Float16)x0.y, (_Float16)x0.z, (_Float16)x0.w,
                   (_Float16)x1.x, (_Float16)x1.y, (_Float16)x1.z, (_Float16)x1.w };
      f16x8 hb = { (_Float16)w0.x, (_Float16)w0.y, (_Float16)w0.z, (_Float16)w0.w,
                   (_Float16)w1.x, (_Float16)w1.y, (_Float16)w1.z, (_Float16)w1.w };
      *(f16x8*)(ldsA + row * 64 + p * 8) = ha;
      *(f16x8*)(ldsB + row * 64 + p * 8) = hb;
    }
    __syncthreads();
#pragma unroll
    for (int s2 = 0; s2 < 2; ++s2) {
      f16x8 af2[4], bf2[4];
#pragma unroll
      for (int m = 0; m < 4; ++m) {
        const int r = wr * 64 + m * 16 + lr;
        af2[m] = *(const f16x8*)(ldsA + r * 64 + (((s2 * 4 + hi) ^ (r & 7)) * 8));
      }
#pragma unroll
      for (int n = 0; n < 4; ++n) {
        const int r = wc * 64 + n * 16 + lr;
        bf2[n] = *(const f16x8*)(ldsB + r * 64 + (((s2 * 4 + hi) ^ (r & 7)) * 8));
      }
#pragma unroll
      for (int m = 0; m < 4; ++m)
#pragma unroll
        for (int n = 0; n < 4; ++n)
          acc[m][n] = __builtin_amdgcn_mfma_f32_16x16x32_f16(af2[m], bf2[n], acc[m][n], 0, 0, 0);
    }
  }
  const float s = scale_p[0];
#pragma unroll
  for (int n = 0; n < 4; ++n) {
    const int col = brow0 + wc * 64 + n * 16 + lr;
    const float bvv = bias[col];
#pragma unroll
    for (int m = 0; m < 4; ++m) {
      const int row0 = arow0 + wr * 64 + m * 16 + hi * 4;
      const f32x4 v = acc[m][n];
#pragma unroll
      for (int j = 0; j < 4; ++j)
        out[(size_t)(row0 + j) * N_TOT + col] = v[j] * s + bvv;
    }
  }
}

// ---------------- launch ----------------

extern "C" void kernel_launch(void* const* d_in, const int* in_sizes, int n_in,
                              void* d_out, int out_size, void* d_ws, size_t ws_size,
                              hipStream_t stream) {
  const float* x     = (const float*)d_in[0];
  const int*   wq    = (const int*)d_in[1];
  const float* scale = (const float*)d_in[2];
  const float* bias  = (const float*)d_in[3];
  float*       out   = (float*)d_out;

  const size_t nA = (size_t)M_TOT * K_TOT;   // 16.7M
  const size_t nB = (size_t)N_TOT * K_TOT;   // 67.1M
  const size_t need = nA + nB + M_TOT * sizeof(float);  // ~84 MiB

  if (ws_size >= need) {
    signed char* A8 = (signed char*)d_ws;
    signed char* B8 = A8 + nA;
    float*       sx = (float*)(B8 + nB);
    cvt_x_i8<<<M_TOT, 256, 0, stream>>>(x, A8, sx);
    cvt_w_i8<<<2048, 256, 0, stream>>>(wq, B8, (int)(nB / 16));
    gemm_i8<<<(M_TOT / BM) * (N_TOT / BN), 1024, 0, stream>>>(A8, B8, sx, scale, bias, out);
  } else {
    gemm_direct<<<(M_TOT / 128) * (N_TOT / 128), 256, 0, stream>>>(x, wq, scale, bias, out);
  }
}

// Round 10
// 447.498 us; speedup vs baseline: 3.7037x; 3.7037x over previous
//
#include <hip/hip_runtime.h>
#include <stdint.h>
#include <stddef.h>

// QuantizedColumnParallel: y[4096,16384] = x[4096,4096] @ (wq[16384,4096]*scale)^T + bias
// R10: DISCRIMINATING EXPERIMENT between the two models that fit the data:
//  (a) alternation: LDS & MFMA pipes serialize in barrier-locked 1-block/CU kernels
//      (in-order waves; all waves phase-aligned) -> fix = 2 blocks/CU co-resident.
//  (b) supply: time = L2/L3 operand bytes / ~6.2 TB/s -> smaller tile = WORSE.
// 128x256 tile, 256 thr (4 waves, 1Mx4N, per-wave 128x64 acc[8][4] as proven),
// 3-buf LDS 72KB -> 2 blocks/CU, launch_bounds(256,2) (VGPR cap 256, need ~196).
// R9 lesson: 1024-thr tiles are register-infeasible (cap 128 = acc alone).

#define M_TOT 4096
#define N_TOT 16384
#define K_TOT 4096
#define NT    64          // K-tiles
#define BM    128
#define BN    256

typedef __attribute__((ext_vector_type(4))) int      v4i;
typedef __attribute__((ext_vector_type(8))) _Float16 f16x8;
typedef __attribute__((ext_vector_type(4))) float    f32x4;

#define GLOAD_LDS16(g, l) __builtin_amdgcn_global_load_lds(                  \
    (const __attribute__((address_space(1))) void*)(g),                      \
    (__attribute__((address_space(3))) void*)(l), 16, 0, 0)

// ---------------- conversion pre-passes ----------------

__global__ __launch_bounds__(256) void cvt_x_i8(const float* __restrict__ x,
                                                signed char* __restrict__ o,
                                                float* __restrict__ sx) {
  const int row = blockIdx.x;
  const int tid = threadIdx.x;
  const float* xr = x + (size_t)row * K_TOT;
  float4 v[4];
  float mx = 0.f;
#pragma unroll
  for (int j = 0; j < 4; ++j) {
    v[j] = ((const float4*)xr)[tid * 4 + j];
    mx = fmaxf(mx, fmaxf(fmaxf(fabsf(v[j].x), fabsf(v[j].y)),
                         fmaxf(fabsf(v[j].z), fabsf(v[j].w))));
  }
#pragma unroll
  for (int off = 32; off; off >>= 1) mx = fmaxf(mx, __shfl_xor(mx, off));
  __shared__ float wm[4];
  if ((tid & 63) == 0) wm[tid >> 6] = mx;
  __syncthreads();
  const float m4 = fmaxf(fmaxf(wm[0], wm[1]), fmaxf(wm[2], wm[3]));
  const float smax = fmaxf(m4, 1e-6f);
  const float inv  = 127.0f / smax;
  if (tid == 0) sx[row] = smax / 127.0f;
  int p[4];
#pragma unroll
  for (int j = 0; j < 4; ++j) {
    int q0 = (int)rintf(v[j].x * inv), q1 = (int)rintf(v[j].y * inv);
    int q2 = (int)rintf(v[j].z * inv), q3 = (int)rintf(v[j].w * inv);
    q0 = max(-127, min(127, q0)); q1 = max(-127, min(127, q1));
    q2 = max(-127, min(127, q2)); q3 = max(-127, min(127, q3));
    p[j] = (q0 & 255) | ((q1 & 255) << 8) | ((q2 & 255) << 16) | (q3 << 24);
  }
  ((int4*)(o + (size_t)row * K_TOT))[tid] = make_int4(p[0], p[1], p[2], p[3]);
}

__global__ __launch_bounds__(256) void cvt_w_i8(const int* __restrict__ w,
                                                signed char* __restrict__ o, int n16) {
  const int stride = gridDim.x * blockDim.x;
  for (int i = blockIdx.x * blockDim.x + threadIdx.x; i < n16; i += stride) {
    int p[4];
#pragma unroll
    for (int j = 0; j < 4; ++j) {
      int4 a = ((const int4*)w)[i * 4 + j];
      p[j] = (a.x & 255) | ((a.y & 255) << 8) | ((a.z & 255) << 16) | (a.w << 24);
    }
    ((int4*)o)[i] = make_int4(p[0], p[1], p[2], p[3]);
  }
}

// ---------------- i8 GEMM: 128x256 tile, 4 waves, 3-buf, 2 blocks/CU ----------------

// Stage A region (128 rows x 64B = 8 KiB): 2 x gload_lds(16B)/thread (256 thr).
// Stage B region (256 rows x 64B = 16 KiB): 4 x gload_lds(16B)/thread.
// LDS dest linear; XOR swizzle on GLOBAL source chunk (rule #21); 64B-row/4-chunk
// geometry identical to R3..R8 (SQ_LDS_BANK_CONFLICT = 0 verified).
__device__ __forceinline__ void stage_A(const signed char* __restrict__ g,
                                        size_t kbyte, signed char* l, int tid) {
#pragma unroll
  for (int j = 0; j < 2; ++j) {
    const int ci  = j * 256 + tid;       // 0..511 chunks
    const int row = ci >> 2;             // 0..127
    const int sc  = (ci & 3) ^ ((row >> 1) & 3);
    GLOAD_LDS16(g + (size_t)row * K_TOT + kbyte + sc * 16, l + ci * 16);
  }
}

__device__ __forceinline__ void stage_B(const signed char* __restrict__ g,
                                        size_t kbyte, signed char* l, int tid) {
#pragma unroll
  for (int j = 0; j < 4; ++j) {
    const int ci  = j * 256 + tid;       // 0..1023 chunks
    const int row = ci >> 2;             // 0..255
    const int sc  = (ci & 3) ^ ((row >> 1) & 3);
    GLOAD_LDS16(g + (size_t)row * K_TOT + kbyte + sc * 16, l + ci * 16);
  }
}

// Swizzled fragment read: row r, 16B chunk hi (0..3).
__device__ __forceinline__ v4i fragi(const signed char* region, int r, int hi) {
  return *(const v4i*)(region + r * 64 + ((hi ^ ((r >> 1) & 3)) << 4));
}

#define BAR()    __builtin_amdgcn_s_barrier()

__global__ __launch_bounds__(256, 2) void gemm_i8(
    const signed char* __restrict__ A8, const signed char* __restrict__ B8,
    const float* __restrict__ sx, const float* __restrict__ scale_p,
    const float* __restrict__ bias, float* __restrict__ out)
{
  // 3 buffers x (A 8K @0 + B 16K @8192) = 72 KiB -> 2 blocks/CU
  __shared__ __align__(16) signed char lds[3][24576];

  const int tid  = threadIdx.x;
  const int lane = tid & 63;
  const int wave = tid >> 6;           // 0..3  (1M x 4N)
  const int wc   = wave;               // N-col of wave
  const int lr = lane & 15;
  const int hi = lane >> 4;

  // XCD swizzle: 2048 wg, 8 XCDs, 256 contiguous per XCD; bm fast (32) so blocks
  // sharing a bn panel (B panel 1 MB <= L2) sit on one XCD.
  const int bid = blockIdx.x;
  const int wg  = (bid & 7) * 256 + (bid >> 3);
  const int bm  = wg & 31;             // 32 M-blocks
  const int bn  = wg >> 5;             // 64 N-blocks
  const int arow0 = bm * BM;
  const int brow0 = bn * BN;

  const signed char* Ag = A8 + (size_t)arow0 * K_TOT;
  const signed char* Bg = B8 + (size_t)brow0 * K_TOT;

  v4i acc[8][4];
#pragma unroll
  for (int m = 0; m < 8; ++m)
#pragma unroll
    for (int n = 0; n < 4; ++n)
      acc[m][n] = (v4i){0, 0, 0, 0};

  // ---- prologue: stage tiles 0,1 (6 insts each); vmcnt(6) => tile0 landed.
  stage_A(Ag, 0,  &lds[0][0],    tid);
  stage_B(Bg, 0,  &lds[0][8192], tid);
  stage_A(Ag, 64, &lds[1][0],    tid);
  stage_B(Bg, 64, &lds[1][8192], tid);
  asm volatile("s_waitcnt vmcnt(6)" ::: "memory");
  BAR();

  for (int t = 0; t < NT; ++t) {
    const signed char* At = &lds[t % 3][0];
    const signed char* Bt = &lds[t % 3][8192];

    // Stage t+2 first (HBM/L2 latency starts earliest).
    if (t + 2 < NT) {
      const size_t k2 = (size_t)(t + 2) * 64;
      signed char* L2p = &lds[(t + 2) % 3][0];
      stage_A(Ag, k2, L2p, tid);
      stage_B(Bg, k2, L2p + 8192, tid);
    }

    // 12 frag reads + 32 MFMAs. Cross-block wave stagger (2 blocks/CU) provides
    // the pipe overlap; setprio biases the CU scheduler toward MFMA-issuing waves.
    v4i af[8], bf[4];
#pragma unroll
    for (int m = 0; m < 8; ++m) af[m] = fragi(At, m * 16 + lr, hi);
#pragma unroll
    for (int n = 0; n < 4; ++n) bf[n] = fragi(Bt, wc * 64 + n * 16 + lr, hi);
    __builtin_amdgcn_s_setprio(1);
#pragma unroll
    for (int m = 0; m < 8; ++m)
#pragma unroll
      for (int n = 0; n < 4; ++n)
        acc[m][n] = __builtin_amdgcn_mfma_i32_16x16x64_i8(af[m], bf[n], acc[m][n], 0, 0, 0);
    __builtin_amdgcn_s_setprio(0);

    // Publish t+1 (oldest 6 landed), keep t+2 (youngest 6) in flight.
    if (t < NT - 2) asm volatile("s_waitcnt vmcnt(6)" ::: "memory");
    else            asm volatile("s_waitcnt vmcnt(0)" ::: "memory");
    BAR();
  }

  // ---- epilogue: y = acc * (sx[row]*scale) + bias.
  // C/D map (dtype-independent): col=lane&15, row=(lane>>4)*4+reg.
  const float s = scale_p[0];
  float bv[4];
#pragma unroll
  for (int n = 0; n < 4; ++n) bv[n] = bias[brow0 + wc * 64 + n * 16 + lr];
#pragma unroll
  for (int mi = 0; mi < 8; ++mi) {
    const int row0 = arow0 + mi * 16 + hi * 4;
    float sc4[4];
#pragma unroll
    for (int j = 0; j < 4; ++j) sc4[j] = sx[row0 + j] * s;
#pragma unroll
    for (int n = 0; n < 4; ++n) {
      const int col = brow0 + wc * 64 + n * 16 + lr;
      const v4i v = acc[mi][n];
#pragma unroll
      for (int j = 0; j < 4; ++j)
        out[(size_t)(row0 + j) * N_TOT + col] = (float)v[j] * sc4[j] + bv[n];
    }
  }
}

// ---------------- fallback (no workspace): f16 DIRECT 128^2 kernel ----------------

__global__ __launch_bounds__(256) void gemm_direct(
    const float* __restrict__ Xf, const int* __restrict__ Wq,
    const float* __restrict__ scale_p, const float* __restrict__ bias,
    float* __restrict__ out)
{
  __shared__ _Float16 ldsA[128 * 64];
  __shared__ _Float16 ldsB[128 * 64];
  const int tid = threadIdx.x, lane = tid & 63, wave = tid >> 6;
  const int wr = wave >> 1, wc = wave & 1;
  const int bid = blockIdx.x;
  const int wg  = (bid & 7) * 512 + (bid >> 3);
  const int arow0 = (wg & 31) * 128, brow0 = (wg >> 5) * 128;
  f32x4 acc[4][4];
#pragma unroll
  for (int m = 0; m < 4; ++m)
#pragma unroll
    for (int n = 0; n < 4; ++n) acc[m][n] = (f32x4){0.f, 0.f, 0.f, 0.f};
  const int srow = tid >> 3, schunk = tid & 7;
  const int lr = lane & 15, hi = lane >> 4;
  for (int kt = 0; kt < K_TOT / 64; ++kt) {
    const size_t kbase = (size_t)kt * 64;
    __syncthreads();
#pragma unroll
    for (int i = 0; i < 4; ++i) {
      const int row = i * 32 + srow;
      const int p = schunk ^ (row & 7);
      const float* gx = Xf + (size_t)(arow0 + row) * K_TOT + kbase + schunk * 8;
      const int*   gw = Wq + (size_t)(brow0 + row) * K_TOT + kbase + schunk * 8;
      float4 x0 = ((const float4*)gx)[0];
      float4 x1 = ((const float4*)gx)[1];
      int4   w0 = ((const int4*)gw)[0];
      int4   w1 = ((const int4*)gw)[1];
      f16x8 ha = { (_Float16)x0.x, (_Float16)x0.y, (_Float16)x0.z, (_Float16)x0.w,
                   (_Float16)x1.x, (_Float16)x1.y, (_Float16)x1.z, (_Float16)x1.w };
      f16x8 hb = { (_Float16)w0.x, (_Float16)w0.y, (_Float16)w0.z, (_Float16)w0.w,
                   (_Float16)w1.x, (_Float16)w1.y, (_Float16)w1.z, (_Float16)w1.w };
      *(f16x8*)(ldsA + row * 64 + p * 8) = ha;
      *(f16x8*)(ldsB + row * 64 + p * 8) = hb;
    }
    __syncthreads();
#pragma unroll
    for (int s2 = 0; s2 < 2; ++s2) {
      f16x8 af2[4], bf2[4];
#pragma unroll
      for (int m = 0; m < 4; ++m) {
        const int r = wr * 64 + m * 16 + lr;
        af2[m] = *(const f16x8*)(ldsA + r * 64 + (((s2 * 4 + hi) ^ (r & 7)) * 8));
      }
#pragma unroll
      for (int n = 0; n < 4; ++n) {
        const int r = wc * 64 + n * 16 + lr;
        bf2[n] = *(const f16x8*)(ldsB + r * 64 + (((s2 * 4 + hi) ^ (r & 7)) * 8));
      }
#pragma unroll
      for (int m = 0; m < 4; ++m)
#pragma unroll
        for (int n = 0; n < 4; ++n)
          acc[m][n] = __builtin_amdgcn_mfma_f32_16x16x32_f16(af2[m], bf2[n], acc[m][n], 0, 0, 0);
    }
  }
  const float s = scale_p[0];
#pragma unroll
  for (int n = 0; n < 4; ++n) {
    const int col = brow0 + wc * 64 + n * 16 + lr;
    const float bvv = bias[col];
#pragma unroll
    for (int m = 0; m < 4; ++m) {
      const int row0 = arow0 + wr * 64 + m * 16 + hi * 4;
      const f32x4 v = acc[m][n];
#pragma unroll
      for (int j = 0; j < 4; ++j)
        out[(size_t)(row0 + j) * N_TOT + col] = v[j] * s + bvv;
    }
  }
}

// ---------------- launch ----------------

extern "C" void kernel_launch(void* const* d_in, const int* in_sizes, int n_in,
                              void* d_out, int out_size, void* d_ws, size_t ws_size,
                              hipStream_t stream) {
  const float* x     = (const float*)d_in[0];
  const int*   wq    = (const int*)d_in[1];
  const float* scale = (const float*)d_in[2];
  const float* bias  = (const float*)d_in[3];
  float*       out   = (float*)d_out;

  const size_t nA = (size_t)M_TOT * K_TOT;   // 16.7M
  const size_t nB = (size_t)N_TOT * K_TOT;   // 67.1M
  const size_t need = nA + nB + M_TOT * sizeof(float);  // ~84 MiB

  if (ws_size >= need) {
    signed char* A8 = (signed char*)d_ws;
    signed char* B8 = A8 + nA;
    float*       sx = (float*)(B8 + nB);
    cvt_x_i8<<<M_TOT, 256, 0, stream>>>(x, A8, sx);
    cvt_w_i8<<<2048, 256, 0, stream>>>(wq, B8, (int)(nB / 16));
    gemm_i8<<<(M_TOT / BM) * (N_TOT / BN), 256, 0, stream>>>(A8, B8, sx, scale, bias, out);
  } else {
    gemm_direct<<<(M_TOT / 128) * (N_TOT / 128), 256, 0, stream>>>(x, wq, scale, bias, out);
  }
}

// Round 11
// 428.844 us; speedup vs baseline: 3.8648x; 1.0435x over previous
//
#include <hip/hip_runtime.h>
#include <stdint.h>
#include <stddef.h>

// QuantizedColumnParallel: y[4096,16384] = x[4096,4096] @ (wq[16384,4096]*scale)^T + bias
// R11: R6 structure + sched_group_barrier-pinned {DS_READ 1, MFMA 4} interleave.
// Ledger (fits R4/R6/R7/R10 +-3%): MFMA 300K + LDSread 295K + stagewrite 65K +
// epilogue 105K cyc/CU, pipes SUMMING because the scheduler hoists all 12 ds_reads
// ahead of the 32 MFMAs in every wave (all barrier-aligned waves flood LDS, then
// all drain matrix). Fix: source order b0-3,a0,a1 then (read a[m+2] || MFMA grp m),
// pinned via T19 spec {VMEM 6}{DS 6} 6x{DS 1, MFMA 4}{MFMA 8}. Read-ahead = 2
// groups (~160 cyc) > LDS latency (~120). Single change vs R6.

#define M_TOT 4096
#define N_TOT 16384
#define K_TOT 4096
#define NT    64          // K-tiles

typedef __attribute__((ext_vector_type(4))) int      v4i;
typedef __attribute__((ext_vector_type(8))) _Float16 f16x8;
typedef __attribute__((ext_vector_type(4))) float    f32x4;

#define GLOAD_LDS16(g, l) __builtin_amdgcn_global_load_lds(                  \
    (const __attribute__((address_space(1))) void*)(g),                      \
    (__attribute__((address_space(3))) void*)(l), 16, 0, 0)

// ---------------- conversion pre-passes ----------------

__global__ __launch_bounds__(256) void cvt_x_i8(const float* __restrict__ x,
                                                signed char* __restrict__ o,
                                                float* __restrict__ sx) {
  const int row = blockIdx.x;
  const int tid = threadIdx.x;
  const float* xr = x + (size_t)row * K_TOT;
  float4 v[4];
  float mx = 0.f;
#pragma unroll
  for (int j = 0; j < 4; ++j) {
    v[j] = ((const float4*)xr)[tid * 4 + j];
    mx = fmaxf(mx, fmaxf(fmaxf(fabsf(v[j].x), fabsf(v[j].y)),
                         fmaxf(fabsf(v[j].z), fabsf(v[j].w))));
  }
#pragma unroll
  for (int off = 32; off; off >>= 1) mx = fmaxf(mx, __shfl_xor(mx, off));
  __shared__ float wm[4];
  if ((tid & 63) == 0) wm[tid >> 6] = mx;
  __syncthreads();
  const float m4 = fmaxf(fmaxf(wm[0], wm[1]), fmaxf(wm[2], wm[3]));
  const float smax = fmaxf(m4, 1e-6f);
  const float inv  = 127.0f / smax;
  if (tid == 0) sx[row] = smax / 127.0f;
  int p[4];
#pragma unroll
  for (int j = 0; j < 4; ++j) {
    int q0 = (int)rintf(v[j].x * inv), q1 = (int)rintf(v[j].y * inv);
    int q2 = (int)rintf(v[j].z * inv), q3 = (int)rintf(v[j].w * inv);
    q0 = max(-127, min(127, q0)); q1 = max(-127, min(127, q1));
    q2 = max(-127, min(127, q2)); q3 = max(-127, min(127, q3));
    p[j] = (q0 & 255) | ((q1 & 255) << 8) | ((q2 & 255) << 16) | (q3 << 24);
  }
  ((int4*)(o + (size_t)row * K_TOT))[tid] = make_int4(p[0], p[1], p[2], p[3]);
}

__global__ __launch_bounds__(256) void cvt_w_i8(const int* __restrict__ w,
                                                signed char* __restrict__ o, int n16) {
  const int stride = gridDim.x * blockDim.x;
  for (int i = blockIdx.x * blockDim.x + threadIdx.x; i < n16; i += stride) {
    int p[4];
#pragma unroll
    for (int j = 0; j < 4; ++j) {
      int4 a = ((const int4*)w)[i * 4 + j];
      p[j] = (a.x & 255) | ((a.y & 255) << 8) | ((a.z & 255) << 16) | (a.w << 24);
    }
    ((int4*)o)[i] = make_int4(p[0], p[1], p[2], p[3]);
  }
}

// ---------------- i8 GEMM: 256^2 tile, pinned interleave, triple-buffered ----------------

__device__ __forceinline__ void stage_i8(const signed char* __restrict__ g,
                                         size_t kbyte, signed char* l, int tid) {
#pragma unroll
  for (int j = 0; j < 2; ++j) {
    const int ci  = j * 512 + tid;       // 0..1023 16B-chunks
    const int row = ci >> 2;             // 0..255
    const int sc  = (ci & 3) ^ ((row >> 1) & 3);
    GLOAD_LDS16(g + (size_t)row * K_TOT + kbyte + sc * 16, l + ci * 16);
  }
}

// Swizzled fragment read: row r, 16B chunk hi (0..3). 2-way aliasing = free.
__device__ __forceinline__ v4i fragi(const signed char* region, int r, int hi) {
  return *(const v4i*)(region + r * 64 + ((hi ^ ((r >> 1) & 3)) << 4));
}

#define BAR()    __builtin_amdgcn_s_barrier()
#define SGB(m,n) __builtin_amdgcn_sched_group_barrier((m), (n), 0)

__global__ __launch_bounds__(512, 2) void gemm_i8(
    const signed char* __restrict__ A8, const signed char* __restrict__ B8,
    const float* __restrict__ sx, const float* __restrict__ scale_p,
    const float* __restrict__ bias, float* __restrict__ out)
{
  // lds[buf(3)][A=0|B=1][256*64 bytes] = 96 KiB -> 1 block/CU
  __shared__ __align__(16) signed char lds[3][2][16384];

  const int tid  = threadIdx.x;
  const int lane = tid & 63;
  const int wave = tid >> 6;
  const int wr = wave >> 2;            // 0..1 (M)
  const int wc = wave & 3;             // 0..3 (N)
  const int lr = lane & 15;
  const int hi = lane >> 4;

  // XCD-aware swizzle: 1024 wg, 8 XCDs, 128 contiguous per XCD; bm fast.
  const int bid = blockIdx.x;
  const int wg  = (bid & 7) * 128 + (bid >> 3);
  const int bm  = wg & 15;
  const int bn  = wg >> 4;
  const int arow0 = bm * 256;
  const int brow0 = bn * 256;

  const signed char* Ag = A8 + (size_t)arow0 * K_TOT;
  const signed char* Bg = B8 + (size_t)brow0 * K_TOT;

  v4i acc[8][4];
#pragma unroll
  for (int m = 0; m < 8; ++m)
#pragma unroll
    for (int n = 0; n < 4; ++n)
      acc[m][n] = (v4i){0, 0, 0, 0};

  // ---- prologue: stage tiles 0,1; vmcnt(4) => tile0 landed, tile1 in flight.
  stage_i8(Ag, 0,  &lds[0][0][0], tid);
  stage_i8(Bg, 0,  &lds[0][1][0], tid);
  stage_i8(Ag, 64, &lds[1][0][0], tid);
  stage_i8(Bg, 64, &lds[1][1][0], tid);
  asm volatile("s_waitcnt vmcnt(4)" ::: "memory");
  BAR();

  for (int t = 0; t < NT; ++t) {
    const signed char* At = &lds[t % 3][0][0];
    const signed char* Bt = &lds[t % 3][1][0];

    // Stage t+2 first (VMEM pipe; latency starts earliest).
    if (t + 2 < NT) {
      const size_t k2 = (size_t)(t + 2) * 64;
      stage_i8(Ag, k2, &lds[(t + 2) % 3][0][0], tid);
      stage_i8(Bg, k2, &lds[(t + 2) % 3][1][0], tid);
    }

    // Source order: b0..b3, a0, a1, then (read a[m+2] || MFMA group m).
    v4i af[8], bf[4];
#pragma unroll
    for (int n = 0; n < 4; ++n) bf[n] = fragi(Bt, wc * 64 + n * 16 + lr, hi);
    af[0] = fragi(At, wr * 128 + 0 * 16 + lr, hi);
    af[1] = fragi(At, wr * 128 + 1 * 16 + lr, hi);
#pragma unroll
    for (int m = 0; m < 8; ++m) {
      if (m + 2 < 8) af[m + 2] = fragi(At, wr * 128 + (m + 2) * 16 + lr, hi);
#pragma unroll
      for (int n = 0; n < 4; ++n)
        acc[m][n] = __builtin_amdgcn_mfma_i32_16x16x64_i8(af[m], bf[n], acc[m][n], 0, 0, 0);
    }

    // T19 schedule spec for this region (encounter-order partition):
    // {VMEM 6 (stage)} {DS 6 (b0-3,a0,a1)} 6x{DS 1, MFMA 4} {MFMA 8}.
    SGB(0x30, 6);        // global_load_lds x6
    SGB(0x100, 6);       // b0..b3, a0, a1
#pragma unroll
    for (int g = 0; g < 6; ++g) { SGB(0x100, 1); SGB(0x8, 4); }
    SGB(0x8, 8);         // MFMA groups 6,7

    // Publish t+1 (oldest 4 landed), keep t+2 (youngest 4) in flight.
    if (t < NT - 2) asm volatile("s_waitcnt vmcnt(4)" ::: "memory");
    else            asm volatile("s_waitcnt vmcnt(0)" ::: "memory");
    BAR();
  }

  // ---- epilogue: y = acc * (sx[row]*scale) + bias.
  // C/D map (dtype-independent): col=lane&15, row=(lane>>4)*4+reg.
  const float s = scale_p[0];
  float bv[4];
#pragma unroll
  for (int n = 0; n < 4; ++n) bv[n] = bias[brow0 + wc * 64 + n * 16 + lr];
#pragma unroll
  for (int mi = 0; mi < 8; ++mi) {
    const int row0 = arow0 + wr * 128 + (mi >> 2) * 64 + (mi & 3) * 16 + hi * 4;
    float sc4[4];
#pragma unroll
    for (int j = 0; j < 4; ++j) sc4[j] = sx[row0 + j] * s;
#pragma unroll
    for (int n = 0; n < 4; ++n) {
      const int col = brow0 + wc * 64 + n * 16 + lr;
      const v4i v = acc[mi][n];
#pragma unroll
      for (int j = 0; j < 4; ++j)
        out[(size_t)(row0 + j) * N_TOT + col] = (float)v[j] * sc4[j] + bv[n];
    }
  }
}

// ---------------- fallback (no workspace): f16 DIRECT 128^2 kernel ----------------

__global__ __launch_bounds__(256) void gemm_direct(
    const float* __restrict__ Xf, const int* __restrict__ Wq,
    const float* __restrict__ scale_p, const float* __restrict__ bias,
    float* __restrict__ out)
{
  __shared__ _Float16 ldsA[128 * 64];
  __shared__ _Float16 ldsB[128 * 64];
  const int tid = threadIdx.x, lane = tid & 63, wave = tid >> 6;
  const int wr = wave >> 1, wc = wave & 1;
  const int bid = blockIdx.x;
  const int wg  = (bid & 7) * 512 + (bid >> 3);
  const int arow0 = (wg & 31) * 128, brow0 = (wg >> 5) * 128;
  f32x4 acc[4][4];
#pragma unroll
  for (int m = 0; m < 4; ++m)
#pragma unroll
    for (int n = 0; n < 4; ++n) acc[m][n] = (f32x4){0.f, 0.f, 0.f, 0.f};
  const int srow = tid >> 3, schunk = tid & 7;
  const int lr = lane & 15, hi = lane >> 4;
  for (int kt = 0; kt < K_TOT / 64; ++kt) {
    const size_t kbase = (size_t)kt * 64;
    __syncthreads();
#pragma unroll
    for (int i = 0; i < 4; ++i) {
      const int row = i * 32 + srow;
      const int p = schunk ^ (row & 7);
      const float* gx = Xf + (size_t)(arow0 + row) * K_TOT + kbase + schunk * 8;
      const int*   gw = Wq + (size_t)(brow0 + row) * K_TOT + kbase + schunk * 8;
      float4 x0 = ((const float4*)gx)[0];
      float4 x1 = ((const float4*)gx)[1];
      int4   w0 = ((const int4*)gw)[0];
      int4   w1 = ((const int4*)gw)[1];
      f16x8 ha = { (_Float16)x0.x, (_Float16)x0.y, (_Float16)x0.z, (_Float16)x0.w,
                   (_Float16)x1.x, (_Float16)x1.y, (_Float16)x1.z, (_Float16)x1.w };
      f16x8 hb = { (_Float16)w0.x, (_Float16)w0.y, (_Float16)w0.z, (_Float16)w0.w,
                   (_Float16)w1.x, (_Float16)w1.y, (_Float16)w1.z, (_Float16)w1.w };
      *(f16x8*)(ldsA + row * 64 + p * 8) = ha;
      *(f16x8*)(ldsB + row * 64 + p * 8) = hb;
    }
    __syncthreads();
#pragma unroll
    for (int s2 = 0; s2 < 2; ++s2) {
      f16x8 af2[4], bf2[4];
#pragma unroll
      for (int m = 0; m < 4; ++m) {
        const int r = wr * 64 + m * 16 + lr;
        af2[m] = *(const f16x8*)(ldsA + r * 64 + (((s2 * 4 + hi) ^ (r & 7)) * 8));
      }
#pragma unroll
      for (int n = 0; n < 4; ++n) {
        const int r = wc * 64 + n * 16 + lr;
        bf2[n] = *(const f16x8*)(ldsB + r * 64 + (((s2 * 4 + hi) ^ (r & 7)) * 8));
      }
#pragma unroll
      for (int m = 0; m < 4; ++m)
#pragma unroll
        for (int n = 0; n < 4; ++n)
          acc[m][n] = __builtin_amdgcn_mfma_f32_16x16x32_f16(af2[m], bf2[n], acc[m][n], 0, 0, 0);
    }
  }
  const float s = scale_p[0];
#pragma unroll
  for (int n = 0; n < 4; ++n) {
    const int col = brow0 + wc * 64 + n * 16 + lr;
    const float bvv = bias[col];
#pragma unroll
    for (int m = 0; m < 4; ++m) {
      const int row0 = arow0 + wr * 64 + m * 16 + hi * 4;
      const f32x4 v = acc[m][n];
#pragma unroll
      for (int j = 0; j < 4; ++j)
        out[(size_t)(row0 + j) * N_TOT + col] = v[j] * s + bvv;
    }
  }
}

// ---------------- launch ----------------

extern "C" void kernel_launch(void* const* d_in, const int* in_sizes, int n_in,
                              void* d_out, int out_size, void* d_ws, size_t ws_size,
                              hipStream_t stream) {
  const float* x     = (const float*)d_in[0];
  const int*   wq    = (const int*)d_in[1];
  const float* scale = (const float*)d_in[2];
  const float* bias  = (const float*)d_in[3];
  float*       out   = (float*)d_out;

  const size_t nA = (size_t)M_TOT * K_TOT;   // 16.7M
  const size_t nB = (size_t)N_TOT * K_TOT;   // 67.1M
  const size_t need = nA + nB + M_TOT * sizeof(float);  // ~84 MiB

  if (ws_size >= need) {
    signed char* A8 = (signed char*)d_ws;
    signed char* B8 = A8 + nA;
    float*       sx = (float*)(B8 + nB);
    cvt_x_i8<<<M_TOT, 256, 0, stream>>>(x, A8, sx);
    cvt_w_i8<<<2048, 256, 0, stream>>>(wq, B8, (int)(nB / 16));
    gemm_i8<<<(M_TOT / 256) * (N_TOT / 256), 512, 0, stream>>>(A8, B8, sx, scale, bias, out);
  } else {
    gemm_direct<<<(M_TOT / 128) * (N_TOT / 128), 256, 0, stream>>>(x, wq, scale, bias, out);
  }
}